// Round 1
// baseline (616.554 us; speedup 1.0000x reference)
//
#include <hip/hip_runtime.h>
#include <hip/hip_bf16.h>
#include <math.h>

#define N 4096
#define DIN 512
#define DOUT 256

typedef short bf16x8 __attribute__((ext_vector_type(8)));
typedef float f32x4 __attribute__((ext_vector_type(4)));

static __device__ __forceinline__ unsigned short f2bf(float x) {
  __hip_bfloat16 b = __float2bfloat16(x);
  return __builtin_bit_cast(unsigned short, b);
}

// ---------------- K1: p[i] = sum_k eta^k sum_o W[k,i,o]*d0[o], q likewise with d1 (f64) ----
__global__ __launch_bounds__(256) void k_pq(const float* __restrict__ W,
                                            const float* __restrict__ disc,
                                            double* __restrict__ p, double* __restrict__ q) {
  __shared__ double lds[8];
  int i = blockIdx.x;   // 0..511
  int t = threadIdx.x;  // 0..255 = o
  double accp = 0.0, accq = 0.0;
  const double wts[3] = {1.0, 0.5, 0.25};
#pragma unroll
  for (int k = 0; k < 3; ++k) {
    double w = (double)W[((size_t)(k * DIN + i)) * DOUT + t];
    accp += wts[k] * w * (double)disc[t];
    accq += wts[k] * w * (double)disc[DOUT + t];
  }
  for (int off = 32; off; off >>= 1) { accp += __shfl_down(accp, off); accq += __shfl_down(accq, off); }
  int l = t & 63, w_ = t >> 6;
  if (l == 0) { lds[w_] = accp; lds[4 + w_] = accq; }
  __syncthreads();
  if (t == 0) {
    p[i] = lds[0] + lds[1] + lds[2] + lds[3];
    q[i] = lds[4] + lds[5] + lds[6] + lds[7];
  }
}

// ---------------- K2: u[n] = sum_i h[n,i]*p[i], v[n] = sum_i h[n,i]*q[i]  (f64) -----------
__global__ __launch_bounds__(256) void k_uv(const float* __restrict__ h,
                                            const double* __restrict__ p, const double* __restrict__ q,
                                            double* __restrict__ u, double* __restrict__ v) {
  __shared__ double lds[8];
  int n = blockIdx.x, t = threadIdx.x;
  double su = 0.0, sv = 0.0;
#pragma unroll
  for (int i = t; i < DIN; i += 256) {
    double hv = (double)h[(size_t)n * DIN + i];
    su += hv * p[i];
    sv += hv * q[i];
  }
  for (int off = 32; off; off >>= 1) { su += __shfl_down(su, off); sv += __shfl_down(sv, off); }
  int l = t & 63, w_ = t >> 6;
  if (l == 0) { lds[w_] = su; lds[4 + w_] = sv; }
  __syncthreads();
  if (t == 0) {
    u[n] = lds[0] + lds[1] + lds[2] + lds[3];
    v[n] = lds[4] + lds[5] + lds[6] + lds[7];
  }
}

// ---------------- K3: denom = max(|min u + min v|, max u + max v); scal[0]=1/denom --------
__global__ __launch_bounds__(1024) void k_denom(const double* __restrict__ u,
                                                const double* __restrict__ v,
                                                double* __restrict__ scal) {
  __shared__ double lds[64];
  int t = threadIdx.x;
  double mnu = 1e300, mxu = -1e300, mnv = 1e300, mxv = -1e300;
#pragma unroll
  for (int k = 0; k < 4; ++k) {
    double uu = u[t + k * 1024], vv = v[t + k * 1024];
    mnu = fmin(mnu, uu); mxu = fmax(mxu, uu);
    mnv = fmin(mnv, vv); mxv = fmax(mxv, vv);
  }
  for (int off = 32; off; off >>= 1) {
    mnu = fmin(mnu, __shfl_down(mnu, off)); mxu = fmax(mxu, __shfl_down(mxu, off));
    mnv = fmin(mnv, __shfl_down(mnv, off)); mxv = fmax(mxv, __shfl_down(mxv, off));
  }
  int l = t & 63, w_ = t >> 6;  // 16 waves
  if (l == 0) { lds[w_] = mnu; lds[16 + w_] = mxu; lds[32 + w_] = mnv; lds[48 + w_] = mxv; }
  __syncthreads();
  if (t == 0) {
    double a = 1e300, b = -1e300, c = 1e300, d = -1e300;
    for (int k = 0; k < 16; ++k) {
      a = fmin(a, lds[k]); b = fmax(b, lds[16 + k]);
      c = fmin(c, lds[32 + k]); d = fmax(d, lds[48 + k]);
    }
    double mn = a + c, mx = b + d;
    double denom = fmax(fabs(mn), mx);
    scal[0] = 1.0 / denom;
  }
}

// ---------------- K4: dn + km planes (the big memory kernel) ------------------------------
__global__ __launch_bounds__(256) void k_dnkm(const int* __restrict__ kmask,
                                              const double* __restrict__ u, const double* __restrict__ v,
                                              const double* __restrict__ scal, const float* __restrict__ lamda,
                                              float* __restrict__ dn, float* __restrict__ kmout) {
  const size_t NN = (size_t)N * N;
  const int* k0 = kmask; const int* k1 = kmask + NN; const int* k2 = kmask + 2 * NN;
  float* km0 = kmout; float* km1 = kmout + NN; float* km2 = kmout + 2 * NN;
  const size_t total4 = NN / 4;
  double inv = scal[0];
  double lam = (double)lamda[0];
  for (size_t idx = (size_t)blockIdx.x * 256 + threadIdx.x; idx < total4;
       idx += (size_t)gridDim.x * 256) {
    int i = (int)(idx >> 10);        // N/4 = 1024 vec4s per row
    int j = (int)(idx & 1023) << 2;
    size_t base = (size_t)i * N + j;
    double ui = u[i];
    double2 va = *(const double2*)(v + j);
    double2 vb = *(const double2*)(v + j + 2);
    double vv[4] = {va.x, va.y, vb.x, vb.y};
    int4 m0 = *(const int4*)(k0 + base);
    int4 m1 = *(const int4*)(k1 + base);
    int4 m2 = *(const int4*)(k2 + base);
    float4 odn, o0, o1, o2;
#pragma unroll
    for (int c = 0; c < 4; ++c) {
      double dnv = (ui + vv[c]) * inv;
      bool pos = dnv > lam, neg = dnv < -lam;
      float dnf = (pos || neg) ? 0.0f : (float)dnv;
      int mk0 = (&m0.x)[c], mk1 = (&m1.x)[c], mk2 = (&m2.x)[c];
      int p0 = pos ? mk0 : 0;
      int p1 = pos ? mk1 : 0;
      int n0 = neg ? mk1 : 0;
      int n1 = neg ? mk2 : 0;
      (&odn.x)[c] = dnf;
      (&o0.x)[c] = (float)(mk0 - p0 - n0);
      (&o1.x)[c] = (float)(mk1 + p0 - p1 + n0 - n1);
      (&o2.x)[c] = (float)(mk2 + p1 + n1);
    }
    *(float4*)(dn + base) = odn;
    *(float4*)(km0 + base) = o0;
    *(float4*)(km1 + base) = o1;
    *(float4*)(km2 + base) = o2;
  }
}

// ---------------- K5: Wh0 = h @ W0 (f32 tiled GEMM), also emits bf16 Wh0^T ----------------
__global__ __launch_bounds__(256) void k_wh0(const float* __restrict__ h, const float* __restrict__ W,
                                             float* __restrict__ Wh0, unsigned short* __restrict__ Wh0T) {
  __shared__ float As[64][20];  // [m][k], stride 20 floats (80B: 16B-aligned rows, no 4-way bank hits)
  __shared__ float Bs[16][72];  // [k][n], stride 72 floats (288B)
  int t = threadIdx.x;
  int i0 = blockIdx.x * 64, o0 = blockIdx.y * 64;
  int tx = t & 15, ty = t >> 4;
  float acc[4][4] = {};
  int am = t >> 2, ak = (t & 3) * 4;   // A staging role
  int bk = t >> 4, bn = (t & 15) * 4;  // B staging role
  for (int kb = 0; kb < DIN; kb += 16) {
    float4 av = *(const float4*)(h + (size_t)(i0 + am) * DIN + kb + ak);
    float4 bv = *(const float4*)(W + (size_t)(kb + bk) * DOUT + o0 + bn);
    *(float4*)&As[am][ak] = av;
    *(float4*)&Bs[bk][bn] = bv;
    __syncthreads();
#pragma unroll
    for (int kk = 0; kk < 16; ++kk) {
      float a0 = As[ty * 4 + 0][kk], a1 = As[ty * 4 + 1][kk];
      float a2 = As[ty * 4 + 2][kk], a3 = As[ty * 4 + 3][kk];
      float4 b = *(const float4*)&Bs[kk][tx * 4];
      acc[0][0] += a0 * b.x; acc[0][1] += a0 * b.y; acc[0][2] += a0 * b.z; acc[0][3] += a0 * b.w;
      acc[1][0] += a1 * b.x; acc[1][1] += a1 * b.y; acc[1][2] += a1 * b.z; acc[1][3] += a1 * b.w;
      acc[2][0] += a2 * b.x; acc[2][1] += a2 * b.y; acc[2][2] += a2 * b.z; acc[2][3] += a2 * b.w;
      acc[3][0] += a3 * b.x; acc[3][1] += a3 * b.y; acc[3][2] += a3 * b.z; acc[3][3] += a3 * b.w;
    }
    __syncthreads();
  }
#pragma unroll
  for (int r = 0; r < 4; ++r) {
    int n = i0 + ty * 4 + r;
    float4 vo = {acc[r][0], acc[r][1], acc[r][2], acc[r][3]};
    *(float4*)(Wh0 + (size_t)n * DOUT + o0 + tx * 4) = vo;
#pragma unroll
    for (int c = 0; c < 4; ++c) {
      Wh0T[(size_t)(o0 + tx * 4 + c) * N + n] = f2bf(acc[r][c]);
    }
  }
}

// ---------------- K6: s1[n] = Wh0[n,:]·a00, s2[n] = Wh0[n,:]·a01 --------------------------
__global__ __launch_bounds__(256) void k_s1s2(const float* __restrict__ Wh0, const float* __restrict__ a,
                                              float* __restrict__ s1, float* __restrict__ s2) {
  __shared__ float lds[8];
  int i = blockIdx.x, t = threadIdx.x;
  float val = Wh0[(size_t)i * DOUT + t];
  float v1 = val * a[t];
  float v2 = val * a[DOUT + t];
  for (int off = 32; off; off >>= 1) { v1 += __shfl_down(v1, off); v2 += __shfl_down(v2, off); }
  int l = t & 63, w_ = t >> 6;
  if (l == 0) { lds[w_] = v1; lds[4 + w_] = v2; }
  __syncthreads();
  if (t == 0) {
    s1[i] = lds[0] + lds[1] + lds[2] + lds[3];
    s2[i] = lds[4] + lds[5] + lds[6] + lds[7];
  }
}

// ---------------- K7: per-row masked softmax stats: m, 1/Z, all-masked flag ---------------
__global__ __launch_bounds__(256) void k_rowstats(const int* __restrict__ k0,
                                                  const float* __restrict__ s1, const float* __restrict__ s2,
                                                  float* __restrict__ mrow, float* __restrict__ zinv,
                                                  int* __restrict__ flag) {
  __shared__ float earr[N];   // 16KB
  __shared__ float redf[4];
  __shared__ int redi[4];
  __shared__ float bm; __shared__ int bc;
  int i = blockIdx.x, t = threadIdx.x;
  float s1i = s1[i];
  float lmax = -1e30f; int lcnt = 0;
  for (int j = t; j < N; j += 256) {
    int mk = k0[(size_t)i * N + j];
    float sv = s1i + s2[j];
    float e = sv >= 0.0f ? sv : 0.2f * sv;
    bool um = mk > 0;
    earr[j] = um ? e : -1e30f;
    if (um) { lmax = fmaxf(lmax, e); lcnt++; }
  }
  for (int off = 32; off; off >>= 1) { lmax = fmaxf(lmax, __shfl_down(lmax, off)); lcnt += __shfl_down(lcnt, off); }
  int l = t & 63, w_ = t >> 6;
  if (l == 0) { redf[w_] = lmax; redi[w_] = lcnt; }
  __syncthreads();
  if (t == 0) {
    bm = fmaxf(fmaxf(redf[0], redf[1]), fmaxf(redf[2], redf[3]));
    bc = redi[0] + redi[1] + redi[2] + redi[3];
  }
  __syncthreads();
  float m = bm; int c = bc;
  float lsum = 0.0f;
  if (c > 0) {
    for (int j = t; j < N; j += 256) {
      float e = earr[j];
      if (e > -1e29f) lsum += expf(e - m);
    }
  }
  for (int off = 32; off; off >>= 1) lsum += __shfl_down(lsum, off);
  if (l == 0) redf[w_] = lsum;
  __syncthreads();
  if (t == 0) {
    float Z = redf[0] + redf[1] + redf[2] + redf[3];
    if (c == 0) { mrow[i] = 0.0f; zinv[i] = 1.0f / (float)N; flag[i] = 1; }
    else        { mrow[i] = m;    zinv[i] = 1.0f / Z;        flag[i] = 0; }
  }
}

// ---------------- K8: out = elu(0.9 * (att @ Wh0) + 0.1 * Wh0), P on-the-fly, bf16 MFMA ---
__global__ __launch_bounds__(256) void k_attn(const int* __restrict__ k0,
                                              const float* __restrict__ s1, const float* __restrict__ s2,
                                              const float* __restrict__ mrow, const float* __restrict__ zinv,
                                              const int* __restrict__ flag,
                                              const float* __restrict__ Wh0, const unsigned short* __restrict__ Wh0T,
                                              float* __restrict__ out) {
  __shared__ unsigned short Ats[16][40];  // 16 x 32 P-tile bf16, row stride 80B (16B aligned)
  int t = threadIdx.x;
  int i0 = blockIdx.x * 16;
  int l = t & 63, w = t >> 6;
  int o0 = w * 64;
  int r = t & 15, c2 = t >> 4;  // staging: thread covers P[r][c2*2], P[r][c2*2+1]
  int irow = i0 + r;
  float s1r = s1[irow], mr = mrow[irow];
  int fl = flag[irow];
  const int* mptr = k0 + (size_t)irow * N + c2 * 2;
  f32x4 acc[4] = {f32x4{0,0,0,0}, f32x4{0,0,0,0}, f32x4{0,0,0,0}, f32x4{0,0,0,0}};
  const unsigned short* bbase = Wh0T + ((size_t)(o0 + (l & 15)) * N + 8 * (l >> 4));
  bf16x8 bn0 = *(const bf16x8*)(bbase + 0 * 16 * N);
  bf16x8 bn1 = *(const bf16x8*)(bbase + 1 * 16 * N);
  bf16x8 bn2 = *(const bf16x8*)(bbase + 2 * 16 * N);
  bf16x8 bn3 = *(const bf16x8*)(bbase + 3 * 16 * N);
  for (int j0 = 0; j0 < N; j0 += 32) {
    // stage A (P tile) into LDS
    int2 mk = *(const int2*)(mptr + j0);
    int j = j0 + c2 * 2;
    float e0 = s1r + s2[j];     e0 = e0 >= 0.0f ? e0 : 0.2f * e0;
    float e1 = s1r + s2[j + 1]; e1 = e1 >= 0.0f ? e1 : 0.2f * e1;
    float p0 = fl ? 1.0f : (mk.x > 0 ? expf(e0 - mr) : 0.0f);
    float p1 = fl ? 1.0f : (mk.y > 0 ? expf(e1 - mr) : 0.0f);
    unsigned int packed = (unsigned int)f2bf(p0) | ((unsigned int)f2bf(p1) << 16);
    *(unsigned int*)(&Ats[r][c2 * 2]) = packed;
    // rotate B prefetch
    bf16x8 bc0 = bn0, bc1 = bn1, bc2 = bn2, bc3 = bn3;
    if (j0 + 32 < N) {
      const unsigned short* nb = bbase + (j0 + 32);
      bn0 = *(const bf16x8*)(nb + 0 * 16 * N);
      bn1 = *(const bf16x8*)(nb + 1 * 16 * N);
      bn2 = *(const bf16x8*)(nb + 2 * 16 * N);
      bn3 = *(const bf16x8*)(nb + 3 * 16 * N);
    }
    __syncthreads();
    bf16x8 af = *(const bf16x8*)(&Ats[l & 15][8 * (l >> 4)]);
    acc[0] = __builtin_amdgcn_mfma_f32_16x16x32_bf16(af, bc0, acc[0], 0, 0, 0);
    acc[1] = __builtin_amdgcn_mfma_f32_16x16x32_bf16(af, bc1, acc[1], 0, 0, 0);
    acc[2] = __builtin_amdgcn_mfma_f32_16x16x32_bf16(af, bc2, acc[2], 0, 0, 0);
    acc[3] = __builtin_amdgcn_mfma_f32_16x16x32_bf16(af, bc3, acc[3], 0, 0, 0);
    __syncthreads();
  }
  // epilogue: C[row=(l>>4)*4+reg][col=l&15] per osub tile
  int col = l & 15, rw = (l >> 4) * 4;
#pragma unroll
  for (int reg = 0; reg < 4; ++reg) {
    int i = i0 + rw + reg;
    float zi = zinv[i];
#pragma unroll
    for (int os = 0; os < 4; ++os) {
      int o = o0 + os * 16 + col;
      float accv = acc[os][reg];
      float val = 0.9f * accv * zi + 0.1f * Wh0[(size_t)i * DOUT + o];
      out[(size_t)i * DOUT + o] = val > 0.0f ? val : expm1f(val);
    }
  }
}

extern "C" void kernel_launch(void* const* d_in, const int* in_sizes, int n_in,
                              void* d_out, int out_size, void* d_ws, size_t ws_size,
                              hipStream_t stream) {
  const float* h     = (const float*)d_in[0];
  const float* W     = (const float*)d_in[1];
  const float* a     = (const float*)d_in[2];
  const float* disc  = (const float*)d_in[3];
  const int*   kmask = (const int*)d_in[4];
  const float* lamda = (const float*)d_in[5];

  float* out = (float*)d_out;                    // [N, DOUT]
  float* dn  = out + (size_t)N * DOUT;           // [N, N]
  float* km  = dn + (size_t)N * N;               // [3, N, N]

  char* ws = (char*)d_ws;
  double* p    = (double*)ws;                          // 4KB
  double* q    = (double*)(ws + 4096);                 // 4KB
  double* u    = (double*)(ws + 8192);                 // 32KB
  double* v    = (double*)(ws + 8192 + 32768);         // 32KB
  double* scal = (double*)(ws + 8192 + 65536);         // 8B (+pad)
  char* ws2 = ws + 8192 + 65536 + 256;
  float* s1   = (float*)ws2;                           // 16KB
  float* s2   = (float*)(ws2 + 16384);                 // 16KB
  float* mrow = (float*)(ws2 + 32768);                 // 16KB
  float* zin  = (float*)(ws2 + 49152);                 // 16KB
  int*   flag = (int*)(ws2 + 65536);                   // 16KB
  float* Wh0  = (float*)(ws2 + 65536 + 16384);         // 4MB
  unsigned short* Wh0T = (unsigned short*)(ws2 + 65536 + 16384 + (size_t)N * DOUT * 4);  // 2MB

  k_pq<<<DIN, 256, 0, stream>>>(W, disc, p, q);
  k_uv<<<N, 256, 0, stream>>>(h, p, q, u, v);
  k_denom<<<1, 1024, 0, stream>>>(u, v, scal);
  k_dnkm<<<4096, 256, 0, stream>>>(kmask, u, v, scal, lamda, dn, km);
  k_wh0<<<dim3(64, 4), 256, 0, stream>>>(h, W, Wh0, Wh0T);
  k_s1s2<<<N, 256, 0, stream>>>(Wh0, a, s1, s2);
  k_rowstats<<<N, 256, 0, stream>>>(kmask, s1, s2, mrow, zin, flag);
  k_attn<<<N / 16, 256, 0, stream>>>(kmask, s1, s2, mrow, zin, flag, Wh0, Wh0T, out);
}